// Round 10
// baseline (106.652 us; speedup 1.0000x reference)
//
#include <hip/hip_runtime.h>
#include <math.h>

#define BB 8
#define CC 64
#define HH 32
#define WW 32
#define HW 1024
#define NEGN 256
#define TEMP 2.0f
#define FACTOR 0.8f
#define EPSF 1e-8f
#define PT 8            // p-rows per block
#define RING 8          // z2 prefetch depth (explicit asm ring)

typedef float f32x4 __attribute__((ext_vector_type(4)));

// workspace layout:
//   simPart[1024*NEGN] f32 | sim0Part[1024] f32 | weight_g[1024*8] f32 |
//   qp[1024*1024] ushort2 (4 MB)
// partials are stored (never accumulated) -> no zeroing pass needed.
// Cross-kernel handoff ONLY across dispatch boundaries (device-coherent).

// ---------------------------------------------------------------------------
// K1 weight_phase: identical to passing R9 kernel (bit-exact).
// ---------------------------------------------------------------------------
__global__ __launch_bounds__(256) void weight_phase(
    const float* __restrict__ img,     // (3, HW)
    const int*   __restrict__ nidx,    // (B, 2, HW, NEG)
    ushort2* __restrict__ qp,          // (B*128, 1024) packed q pairs
    float* __restrict__ weight_g)      // (B*128, 8)
{
    __shared__ float imgs_l[3 * HW];   // 12 KB

    const int t   = threadIdx.x;
    const int blk = blockIdx.x;        // = b*128 + pblk
    const int b   = blk >> 7;
    const int p0  = (blk & 127) * PT;

    const int lane32 = t & 31;
    const int pp_b   = t >> 5;
    const int p_b    = p0 + pp_b;

    const size_t nbase = ((size_t)(b * 2) * HW + p_b) * NEGN;
    const int2* __restrict__ nr = reinterpret_cast<const int2*>(nidx + nbase);
    const int2* __restrict__ nc =
        reinterpret_cast<const int2*>(nidx + nbase + (size_t)HW * NEGN);
    int2 rrv[4], ccv[4];
    #pragma unroll
    for (int j = 0; j < 4; ++j) {
        rrv[j] = nr[lane32 + 32 * j];
        ccv[j] = nc[lane32 + 32 * j];
    }

    {
        const float4* __restrict__ imgf4 = reinterpret_cast<const float4*>(img);
        float4* imgs4 = reinterpret_cast<float4*>(imgs_l);
        #pragma unroll
        for (int j = 0; j < 3; ++j) imgs4[t + 256 * j] = imgf4[t + 256 * j];
    }
    __syncthreads();

    const float cen0 = imgs_l[p_b], cen1 = imgs_l[HW + p_b], cen2 = imgs_l[2 * HW + p_b];
    const float hp = (float)(p_b >> 5), wp = (float)(p_b & 31);

    int q[8];
    #pragma unroll
    for (int j = 0; j < 4; ++j) {
        q[2 * j]     = rrv[j].x * WW + ccv[j].x;
        q[2 * j + 1] = rrv[j].y * WW + ccv[j].y;
    }
    float g0[8], g1[8], g2[8];
    #pragma unroll
    for (int e = 0; e < 8; ++e) {
        g0[e] = imgs_l[q[e]];
        g1[e] = imgs_l[HW + q[e]];
        g2[e] = imgs_l[2 * HW + q[e]];
    }
    float se = 0.f, sr = 0.f;
    #pragma unroll
    for (int j = 0; j < 4; ++j) {
        {
            const float dh = hp - (float)rrv[j].x, dw = wp - (float)ccv[j].x;
            se += dh * dh + dw * dw;
            const float d0 = cen0 - g0[2 * j];
            const float d1 = cen1 - g1[2 * j];
            const float d2 = cen2 - g2[2 * j];
            sr += d0 * d0 + d1 * d1 + d2 * d2;
        }
        {
            const float dh = hp - (float)rrv[j].y, dw = wp - (float)ccv[j].y;
            se += dh * dh + dw * dw;
            const float d0 = cen0 - g0[2 * j + 1];
            const float d1 = cen1 - g1[2 * j + 1];
            const float d2 = cen2 - g2[2 * j + 1];
            sr += d0 * d0 + d1 * d1 + d2 * d2;
        }
    }
    #pragma unroll
    for (int off = 16; off; off >>= 1) {
        se += __shfl_xor(se, off);
        sr += __shfl_xor(sr, off);
    }
    const float euc_norm = sqrtf((float)((HH - 1) * (HH - 1) + (WW - 1) * (WW - 1)));
    const float weight = sqrtf(se) / euc_norm * FACTOR +
                         sqrtf(sr) / sqrtf(3.0f) * (1.0f - FACTOR);

    ushort2* qrow = qp + (size_t)blk * 1024;
    #pragma unroll
    for (int j = 0; j < 4; ++j)
        qrow[pp_b * 128 + lane32 + 32 * j] =
            make_ushort2((unsigned short)q[2 * j], (unsigned short)q[2 * j + 1]);
    if (lane32 == 0) weight_g[blk * 8 + pp_b] = weight;
}

// ---------------------------------------------------------------------------
// K2 gemm_sim: R9 structure; the z2 stream is now an EXPLICIT inline-asm
// prefetch ring with counted s_waitcnt vmcnt(N) (T3/T4):
//   - R8 counters showed VGPR_Count=64 although source declares 64 VGPRs of
//     acc+ring alone -> hipcc was collapsing the ring to just-in-time loads
//     with near-vmcnt(0) waits (the §5 compiler-defeats-pipelining mode).
//   - asm outputs force all 8 ring registers live; each consume is preceded
//     by an asm "s_waitcnt vmcnt(7)" that "+v"-ties the consumed register,
//     giving the FMAs a true RAW dep on the wait (no hoisting hazard).
//   - vmcnt never drains to 0 in the main loop; drain uses vmcnt(6..0).
// Arithmetic and op order bit-identical to passing R9.
// LDS: 2 + 32 + ~0.1 = 34.1 KB -> 4 workgroups/CU; grid 1024 = 4/CU.
// ---------------------------------------------------------------------------
__global__ __launch_bounds__(256, 4) void gemm_sim(
    const float* __restrict__ z1,      // (B, C, HW)
    const float* __restrict__ z2,      // (B, C, HW)
    const ushort2* __restrict__ qp,    // (B*128, 1024)
    const float* __restrict__ weight_g,// (B*128, 8)
    float* __restrict__ simPart,       // (B*128, NEG)
    float* __restrict__ sim0Part)      // (B*128)
{
    __shared__ float As_s[CC * PT];    // [c][pp]   2 KB
    __shared__ float Dt_s[PT * HW];    // 32 KB: cos, later simpart alias
    __shared__ float z1n_s[PT];
    __shared__ float z1sq_s[PT];

    const int t   = threadIdx.x;
    const int blk = blockIdx.x;        // = b*128 + pblk
    const int b   = blk >> 7;
    const int p0  = (blk & 127) * PT;

    const int lane32 = t & 31;
    const int pp_b   = t >> 5;

    // ---- stage z1 panel ----
    for (int i = t; i < CC * PT; i += 256) {
        const int c = i >> 3, pp = i & 7;
        As_s[i] = z1[((size_t)(b * CC + c)) * HW + p0 + pp];
    }

    // ---- issue z2 ring prologue (asm; drained by the barrier, refills
    //      in the first 8 loop iterations) ----
    const float* z2b = z2 + (size_t)b * CC * HW;   // uniform -> SGPR pair
    const unsigned vo = (unsigned)(t * 16);        // byte offset in a 4KB k-row
    f32x4 pf[RING];
    #pragma unroll
    for (int i = 0; i < RING; ++i) {
        asm volatile("global_load_dwordx4 %0, %1, %2"
                     : "=v"(pf[i])
                     : "v"(vo + (unsigned)(i * 4096)), "s"(z2b));
    }

    __syncthreads();

    // ---- z1sq / z1n (linear c-order, bit-exact w/ reference) ----
    {
        const int pp = t & 7;
        float s = 0.f;
        #pragma unroll
        for (int c = 0; c < CC; ++c) { const float v = As_s[c * PT + pp]; s += v * v; }
        if (t < PT) { z1sq_s[t] = s; z1n_s[t] = sqrtf(s); }
    }
    __syncthreads();

    if (t == 0) {      // sim0 partial for this block
        float s0 = 0.f;
        #pragma unroll
        for (int pp = 0; pp < PT; ++pp)
            s0 += fminf(fabsf(z1sq_s[pp] / fmaxf(z1sq_s[pp], EPSF)), 1.0f);
        sim0Part[blk] = s0;
    }

    // ---- GEMM: thread t owns q = 4t..4t+3 for all 8 p ----
    float4 acc[PT];
    #pragma unroll
    for (int pp = 0; pp < PT; ++pp) acc[pp] = make_float4(0.f, 0.f, 0.f, 0.f);
    float4 sq = make_float4(0.f, 0.f, 0.f, 0.f);

#define GEMM_STEP(kk, bv)                                                      \
    {                                                                          \
        sq.x = fmaf((bv).x, (bv).x, sq.x);                                     \
        sq.y = fmaf((bv).y, (bv).y, sq.y);                                     \
        sq.z = fmaf((bv).z, (bv).z, sq.z);                                     \
        sq.w = fmaf((bv).w, (bv).w, sq.w);                                     \
        const float4 a03 = reinterpret_cast<const float4*>(As_s)[(kk) * 2];    \
        const float4 a47 = reinterpret_cast<const float4*>(As_s)[(kk) * 2 + 1];\
        const float av[8] = {a03.x, a03.y, a03.z, a03.w,                       \
                             a47.x, a47.y, a47.z, a47.w};                      \
        _Pragma("unroll")                                                      \
        for (int pp = 0; pp < PT; ++pp) {                                      \
            acc[pp].x = fmaf(av[pp], (bv).x, acc[pp].x);                       \
            acc[pp].y = fmaf(av[pp], (bv).y, acc[pp].y);                       \
            acc[pp].z = fmaf(av[pp], (bv).z, acc[pp].z);                       \
            acc[pp].w = fmaf(av[pp], (bv).w, acc[pp].w);                       \
        }                                                                      \
    }

    // main loop: counted vmcnt(7) per consume (never 0); reissue after use
    #pragma unroll 8
    for (int k = 0; k < CC - RING; ++k) {           // 56 iters
        asm volatile("s_waitcnt vmcnt(7)" : "+v"(pf[k & (RING - 1)]));
        GEMM_STEP(k, pf[k & (RING - 1)]);
        asm volatile("global_load_dwordx4 %0, %1, %2"
                     : "=v"(pf[k & (RING - 1)])
                     : "v"(vo + (unsigned)((k + RING) * 4096)), "s"(z2b));
    }
    // drain: vmcnt(6..0)
    #pragma unroll
    for (int j = 0; j < RING; ++j) {
        const int k = CC - RING + j;
        asm volatile("s_waitcnt vmcnt(%1)"
                     : "+v"(pf[k & (RING - 1)])
                     : "i"(RING - 1 - j));
        GEMM_STEP(k, pf[k & (RING - 1)]);
    }
#undef GEMM_STEP

    // ---- epilogue: dot -> cos, store in Dt_s ----
    float z1nv[PT];
    #pragma unroll
    for (int pp = 0; pp < PT; ++pp) z1nv[pp] = z1n_s[pp];
    const float4 pnn = make_float4(sqrtf(sq.x), sqrtf(sq.y),
                                   sqrtf(sq.z), sqrtf(sq.w));
    float4* Dt4 = reinterpret_cast<float4*>(Dt_s);
    #pragma unroll
    for (int pp = 0; pp < PT; ++pp) {
        float4 cv;
        cv.x = acc[pp].x / fmaxf(z1nv[pp] * pnn.x, EPSF);
        cv.y = acc[pp].y / fmaxf(z1nv[pp] * pnn.y, EPSF);
        cv.z = acc[pp].z / fmaxf(z1nv[pp] * pnn.z, EPSF);
        cv.w = acc[pp].w / fmaxf(z1nv[pp] * pnn.w, EPSF);
        Dt4[pp * (HW / 4) + t] = cv;
    }

    // ---- read back q + weight (issued before the barrier) ----
    const ushort2* qrow = qp + (size_t)blk * 1024;
    ushort2 qv[4];
    #pragma unroll
    for (int j = 0; j < 4; ++j) qv[j] = qrow[pp_b * 128 + lane32 + 32 * j];
    const float weight = weight_g[blk * 8 + pp_b];
    __syncthreads();

    // ---- gather cos at q's, combine with weight ----
    float cg[8];
    #pragma unroll
    for (int j = 0; j < 4; ++j) {
        cg[2 * j]     = Dt_s[pp_b * HW + qv[j].x];
        cg[2 * j + 1] = Dt_s[pp_b * HW + qv[j].y];
    }
    float2 sv[4];
    #pragma unroll
    for (int j = 0; j < 4; ++j) {
        sv[j].x = fminf(fabsf(cg[2 * j]     * weight), 1.0f);
        sv[j].y = fminf(fabsf(cg[2 * j + 1] * weight), 1.0f);
    }

    __syncthreads();                       // all Dt_s reads done -> alias safe
    float2* simpart2 = reinterpret_cast<float2*>(Dt_s);  // [pp][n/2], 8 KB
    #pragma unroll
    for (int j = 0; j < 4; ++j)
        simpart2[pp_b * (NEGN / 2) + lane32 + 32 * j] = sv[j];
    __syncthreads();

    // per-n sum over the 8 p's (ascending pp = ascending p) -> plain store
    float s = 0.f;
    #pragma unroll
    for (int pp = 0; pp < PT; ++pp) s += Dt_s[pp * NEGN + t];
    simPart[(size_t)blk * NEGN + t] = s;
}

// ---------------------------------------------------------------------------
// reduce_out: identical to passing R9 kernel.
// ---------------------------------------------------------------------------
__global__ __launch_bounds__(256) void reduce_out(
    const float* __restrict__ simPart,   // (B*128, NEG)
    const float* __restrict__ sim0Part,  // (B*128)
    float* __restrict__ out)             // (3), pre-zeroed by harness
{
    const int b = blockIdx.x;
    const int t = threadIdx.x;

    float a = 0.f;
    #pragma unroll 8
    for (int pblk = 0; pblk < 128; ++pblk)          // ascending p order
        a += simPart[((size_t)(b * 128 + pblk)) * NEGN + t];

    const float s = a * (1.0f / HW) * (1.0f / TEMP);       // sim_b[n+1]
    float ssum = s;
    float lsum = fmaxf(log1pf(-s), -100.0f);

    __shared__ float rs[4], rl[4];
    __shared__ float s0sh;
    #pragma unroll
    for (int off = 32; off; off >>= 1) {
        ssum += __shfl_down(ssum, off);
        lsum += __shfl_down(lsum, off);
    }
    if ((t & 63) == 0) { rs[t >> 6] = ssum; rl[t >> 6] = lsum; }

    if (t < 64) {
        float v = sim0Part[b * 128 + t] + sim0Part[b * 128 + 64 + t];
        #pragma unroll
        for (int off = 32; off; off >>= 1) v += __shfl_xor(v, off);
        if (t == 0) s0sh = v * (1.0f / HW);                 // sim_b[0]
    }
    __syncthreads();

    if (t == 0) {
        const float S = rs[0] + rs[1] + rs[2] + rs[3];
        const float L = rl[0] + rl[1] + rl[2] + rl[3];
        const float s0 = s0sh;
        const float logp = fmaxf(logf(s0), -100.0f);
        atomicAdd(out + 0, -(logp + L) / ((float)(NEGN + 1) * (float)BB));
        atomicAdd(out + 1, s0 / (float)BB);
        atomicAdd(out + 2, S / (float)NEGN * TEMP / (float)BB);
    }
}

extern "C" void kernel_launch(void* const* d_in, const int* in_sizes, int n_in,
                              void* d_out, int out_size, void* d_ws, size_t ws_size,
                              hipStream_t stream) {
    const float* v1   = (const float*)d_in[0];
    const float* v2   = (const float*)d_in[1];
    const float* img  = (const float*)d_in[2];
    const int*   nidx = (const int*)  d_in[3];

    float*   simPart  = (float*)d_ws;                  // 1024*NEGN f32
    float*   sim0Part = simPart + 1024 * NEGN;         // 1024 f32
    float*   weight_g = sim0Part + 1024;               // 1024*8 f32
    ushort2* qp       = (ushort2*)(weight_g + 1024 * 8); // 1024*1024 ushort2

    weight_phase<<<BB * (HW / PT), 256, 0, stream>>>(img, nidx, qp, weight_g);
    gemm_sim<<<BB * (HW / PT), 256, 0, stream>>>(
        v1, v2, qp, weight_g, simPart, sim0Part);
    reduce_out<<<BB, 256, 0, stream>>>(simPart, sim0Part, (float*)d_out);
}

// Round 11
// 91.353 us; speedup vs baseline: 1.1675x; 1.1675x over previous
//
#include <hip/hip_runtime.h>
#include <math.h>

#define BB 8
#define CC 64
#define HH 32
#define WW 32
#define HW 1024
#define NEGN 256
#define TEMP 2.0f
#define FACTOR 0.8f
#define EPSF 1e-8f

typedef short bf16x8 __attribute__((ext_vector_type(8)));
typedef float f32x4  __attribute__((ext_vector_type(4)));

__device__ inline unsigned short f2bf(float f) {     // RNE fp32 -> bf16
    unsigned u = __float_as_uint(f);
    u += 0x7FFFu + ((u >> 16) & 1u);
    return (unsigned short)(u >> 16);
}

// workspace (bytes, all 16B-aligned):
//  simPart f32[512*256] | sim0Part f32[512] | weight_g f32[8192] |
//  z1n f32[8192] | normq f32[8192] | qp ushort2[1048576] |
//  z1t u16[8*1024*64] | z2t u16[8*1024*64]
// partials stored, never accumulated; cross-kernel handoff only across
// dispatch boundaries.

// ---------------------------------------------------------------------------
// K1 prep: (a) weight phase BIT-IDENTICAL to the passing R9/R10 kernel
// (nidx -> q pairs + per-p weight); (b) converts one 16-row tile of z1 or z2
// to bf16 TRANSPOSED [row][c] layout (c contiguous -> 16B MFMA frag loads),
// computing fp32 norms (z1n / normq) and sim0 partials from the ORIGINAL
// fp32 values (only the dot product is bf16-approximated downstream).
// grid 1024: every block does one weight-tile (8p) and one convert-tile
// (16 rows; blk<512 -> z1, else z2).
// ---------------------------------------------------------------------------
__global__ __launch_bounds__(256) void prep(
    const float* __restrict__ z1,      // (B, C, HW)
    const float* __restrict__ z2,      // (B, C, HW)
    const float* __restrict__ img,     // (3, HW)
    const int*   __restrict__ nidx,    // (B, 2, HW, NEG)
    ushort2* __restrict__ qp,          // [(b*1024+p)*128 + npair]
    float* __restrict__ weight_g,      // [b*1024 + p]
    unsigned short* __restrict__ z1t,  // (B*1024 rows, 64 c) bf16
    unsigned short* __restrict__ z2t,  // (B*1024 rows, 64 c) bf16
    float* __restrict__ z1n_ws,        // (B*1024)
    float* __restrict__ normq_ws,      // (B*1024)
    float* __restrict__ sim0Part)      // (512) per z1-tile
{
    __shared__ float imgs_l[3 * HW];   // 12 KB
    __shared__ float ctile[64 * 16];   // [c][row] fp32, 4 KB
    __shared__ float csq[16];

    const int t   = threadIdx.x;
    const int blk = blockIdx.x;

    // ---------------- weight-phase ids (8-row tiles, as R9) ----------------
    const int b_w  = blk >> 7;
    const int p0_8 = (blk & 127) * 8;
    const int lane32 = t & 31;
    const int pp_w   = t >> 5;
    const int p_w    = p0_8 + pp_w;

    // ---------------- convert ids (16-row tiles) ----------------
    const bool isZ1 = (blk < 512);
    const int cvt   = isZ1 ? blk : blk - 512;
    const int b_c   = cvt >> 6;
    const int p0c   = (cvt & 63) * 16;
    const float* __restrict__ src = isZ1 ? z1 : z2;

    // nidx loads first (cold HBM latency overlaps staging)
    const size_t nbase = ((size_t)(b_w * 2) * HW + p_w) * NEGN;
    const int2* __restrict__ nr = reinterpret_cast<const int2*>(nidx + nbase);
    const int2* __restrict__ nc =
        reinterpret_cast<const int2*>(nidx + nbase + (size_t)HW * NEGN);
    int2 rrv[4], ccv[4];
    #pragma unroll
    for (int j = 0; j < 4; ++j) {
        rrv[j] = nr[lane32 + 32 * j];
        ccv[j] = nc[lane32 + 32 * j];
    }

    {   // stage img
        const float4* __restrict__ imgf4 = reinterpret_cast<const float4*>(img);
        float4* imgs4 = reinterpret_cast<float4*>(imgs_l);
        #pragma unroll
        for (int j = 0; j < 3; ++j) imgs4[t + 256 * j] = imgf4[t + 256 * j];
    }
    {   // stage convert tile: idx = c*16 + row
        #pragma unroll
        for (int i = 0; i < 4; ++i) {
            const int idx = t + 256 * i;
            const int c = idx >> 4, row = idx & 15;
            ctile[idx] = src[((size_t)(b_c * CC + c)) * HW + p0c + row];
        }
    }
    __syncthreads();

    // ---------------- weight compute (bit-identical to R9) ----------------
    {
        const float cen0 = imgs_l[p_w], cen1 = imgs_l[HW + p_w], cen2 = imgs_l[2 * HW + p_w];
        const float hp = (float)(p_w >> 5), wp = (float)(p_w & 31);

        int q[8];
        #pragma unroll
        for (int j = 0; j < 4; ++j) {
            q[2 * j]     = rrv[j].x * WW + ccv[j].x;
            q[2 * j + 1] = rrv[j].y * WW + ccv[j].y;
        }
        float g0[8], g1[8], g2[8];
        #pragma unroll
        for (int e = 0; e < 8; ++e) {
            g0[e] = imgs_l[q[e]];
            g1[e] = imgs_l[HW + q[e]];
            g2[e] = imgs_l[2 * HW + q[e]];
        }
        float se = 0.f, sr = 0.f;
        #pragma unroll
        for (int j = 0; j < 4; ++j) {
            {
                const float dh = hp - (float)rrv[j].x, dw = wp - (float)ccv[j].x;
                se += dh * dh + dw * dw;
                const float d0 = cen0 - g0[2 * j];
                const float d1 = cen1 - g1[2 * j];
                const float d2 = cen2 - g2[2 * j];
                sr += d0 * d0 + d1 * d1 + d2 * d2;
            }
            {
                const float dh = hp - (float)rrv[j].y, dw = wp - (float)ccv[j].y;
                se += dh * dh + dw * dw;
                const float d0 = cen0 - g0[2 * j + 1];
                const float d1 = cen1 - g1[2 * j + 1];
                const float d2 = cen2 - g2[2 * j + 1];
                sr += d0 * d0 + d1 * d1 + d2 * d2;
            }
        }
        #pragma unroll
        for (int off = 16; off; off >>= 1) {
            se += __shfl_xor(se, off);
            sr += __shfl_xor(sr, off);
        }
        const float euc_norm = sqrtf((float)((HH - 1) * (HH - 1) + (WW - 1) * (WW - 1)));
        const float weight = sqrtf(se) / euc_norm * FACTOR +
                             sqrtf(sr) / sqrtf(3.0f) * (1.0f - FACTOR);

        ushort2* qrow = qp + (size_t)(b_w * 1024 + p0_8) * 128;
        #pragma unroll
        for (int j = 0; j < 4; ++j)
            qrow[pp_w * 128 + lane32 + 32 * j] =
                make_ushort2((unsigned short)q[2 * j], (unsigned short)q[2 * j + 1]);
        if (lane32 == 0) weight_g[b_w * 1024 + p_w] = weight;
    }

    // ---------------- norms from fp32 (linear c order) ----------------
    if (t < 16) {
        float s = 0.f;
        #pragma unroll
        for (int c = 0; c < CC; ++c) { const float v = ctile[c * 16 + t]; s += v * v; }
        if (isZ1) {
            z1n_ws[b_c * 1024 + p0c + t] = sqrtf(s);
            csq[t] = fminf(fabsf(s / fmaxf(s, EPSF)), 1.0f);
        } else {
            normq_ws[b_c * 1024 + p0c + t] = sqrtf(s);
        }
    }
    __syncthreads();
    if (isZ1 && t == 0) {
        float s0 = 0.f;
        #pragma unroll
        for (int i = 0; i < 16; ++i) s0 += csq[i];
        sim0Part[cvt] = s0;
    }

    // ---------------- bf16 transpose-store: out[row][c], c contiguous ------
    {
        unsigned short* dst =
            (isZ1 ? z1t : z2t) + ((size_t)(b_c * 1024) + p0c) * 64;
        ushort4 pk;
        const int o = 4 * t;                 // o = row*64 + c
        pk.x = f2bf(ctile[((o + 0) & 63) * 16 + ((o + 0) >> 6)]);
        pk.y = f2bf(ctile[((o + 1) & 63) * 16 + ((o + 1) >> 6)]);
        pk.z = f2bf(ctile[((o + 2) & 63) * 16 + ((o + 2) >> 6)]);
        pk.w = f2bf(ctile[((o + 3) & 63) * 16 + ((o + 3) >> 6)]);
        *reinterpret_cast<ushort4*>(dst + o) = pk;
    }
}

// ---------------------------------------------------------------------------
// K2 gemm_mfma: one block per (b, 16-p tile); 4 waves; wave w owns q in
// [w*256, w*256+256). Per 16x16 q-tile: 2x mfma_f32_16x16x32_bf16 (K=64).
// A-frag (shared by all tiles): z1t row p0+(lane&15), k-chunk (lane>>4)*8
// (any bijective k-assignment is valid since A and B use the same one).
// Epilogue: cos = acc/max(z1n*pnn, EPS) -> Dt_s[row][q] (C/D layout per m89:
// col = lane&15, row = (lane>>4)*4 + reg).
// Phase B: thread t -> p = t>>4, 8 q-pairs; gather cos from LDS, combine
// with weight, per-n block sums -> plain store. LDS 68.3 KB -> 2 blocks/CU.
// ---------------------------------------------------------------------------
__global__ __launch_bounds__(256, 2) void gemm_mfma(
    const unsigned short* __restrict__ z1t,   // (B*1024, 64) bf16
    const unsigned short* __restrict__ z2t,   // (B*1024, 64) bf16
    const float* __restrict__ z1n_ws,         // (B*1024)
    const float* __restrict__ normq_ws,       // (B*1024)
    const ushort2* __restrict__ qp,           // [(b*1024+p)*128 + npair]
    const float* __restrict__ weight_g,       // [b*1024 + p]
    float* __restrict__ simPart)              // (512, NEG)
{
    __shared__ float Dt_s[16 * HW];    // 64 KB cos, later simpart alias
    __shared__ float nq_s[HW];         // 4 KB
    __shared__ float z1n_s[16];

    const int t    = threadIdx.x;
    const int blk  = blockIdx.x;       // = b*64 + ptile
    const int b    = blk >> 6;
    const int p0   = (blk & 63) * 16;
    const int wave = t >> 6;
    const int lane = t & 63;
    const int ln15 = lane & 15;
    const int lg   = lane >> 4;        // k-chunk group 0..3

    // stage per-q norms + per-p norms
    reinterpret_cast<float4*>(nq_s)[t] =
        reinterpret_cast<const float4*>(normq_ws + b * 1024)[t];
    if (t < 16) z1n_s[t] = z1n_ws[b * 1024 + p0 + t];

    // A fragments (reused for all q-tiles): row p0+ln15, k = lg*8 + j (+32)
    const unsigned short* arow =
        z1t + ((size_t)(b * 1024) + p0 + ln15) * 64 + lg * 8;
    const bf16x8 a0 = *reinterpret_cast<const bf16x8*>(arow);
    const bf16x8 a1 = *reinterpret_cast<const bf16x8*>(arow + 32);

    __syncthreads();

    // ---- MFMA over this wave's 16 q-tiles ----
    const int qw = wave * 256;
    #pragma unroll 4
    for (int tile = 0; tile < 16; ++tile) {
        const int q0 = qw + tile * 16;
        const unsigned short* brow =
            z2t + ((size_t)(b * 1024) + q0 + ln15) * 64 + lg * 8;
        const bf16x8 b0 = *reinterpret_cast<const bf16x8*>(brow);
        const bf16x8 b1 = *reinterpret_cast<const bf16x8*>(brow + 32);
        f32x4 acc = {0.f, 0.f, 0.f, 0.f};
        acc = __builtin_amdgcn_mfma_f32_16x16x32_bf16(a0, b0, acc, 0, 0, 0);
        acc = __builtin_amdgcn_mfma_f32_16x16x32_bf16(a1, b1, acc, 0, 0, 0);

        const float pn = nq_s[q0 + ln15];
        #pragma unroll
        for (int i = 0; i < 4; ++i) {
            const int row = lg * 4 + i;
            Dt_s[row * HW + q0 + ln15] = acc[i] / fmaxf(z1n_s[row] * pn, EPSF);
        }
    }

    // phase-B operand loads (independent of Dt_s; issue before the barrier)
    const int p_b = t >> 4;            // 0..15
    const int tn  = t & 15;
    const ushort2* qrow = qp + (size_t)(b * 1024 + p0 + p_b) * 128;
    ushort2 qv[8];
    #pragma unroll
    for (int j = 0; j < 8; ++j) qv[j] = qrow[tn + 16 * j];
    const float weight = weight_g[b * 1024 + p0 + p_b];
    __syncthreads();

    // ---- gather cos, combine with weight ----
    float2 sv[8];
    #pragma unroll
    for (int j = 0; j < 8; ++j) {
        const float c0 = Dt_s[p_b * HW + qv[j].x];
        const float c1 = Dt_s[p_b * HW + qv[j].y];
        sv[j].x = fminf(fabsf(c0 * weight), 1.0f);
        sv[j].y = fminf(fabsf(c1 * weight), 1.0f);
    }
    __syncthreads();                       // Dt_s reads done -> alias safe

    float2* simpart2 = reinterpret_cast<float2*>(Dt_s);  // [16][128] f2
    #pragma unroll
    for (int j = 0; j < 8; ++j)
        simpart2[p_b * (NEGN / 2) + tn + 16 * j] = sv[j];
    __syncthreads();

    // per-n sum over the 16 p's (ascending p) -> plain store
    float s = 0.f;
    #pragma unroll
    for (int pp = 0; pp < 16; ++pp) s += Dt_s[pp * NEGN + t];
    simPart[(size_t)blk * NEGN + t] = s;
}

// ---------------------------------------------------------------------------
// reduce_out: 8 blocks (one per b). Sums 64 p-tile partials per n (ascending
// p), assembles per-b loss terms, atomicAdd into harness-zeroed out[3].
// ---------------------------------------------------------------------------
__global__ __launch_bounds__(256) void reduce_out(
    const float* __restrict__ simPart,   // (512, NEG)
    const float* __restrict__ sim0Part,  // (512)
    float* __restrict__ out)
{
    const int b = blockIdx.x;
    const int t = threadIdx.x;

    float a = 0.f;
    #pragma unroll 8
    for (int pblk = 0; pblk < 64; ++pblk)
        a += simPart[((size_t)(b * 64 + pblk)) * NEGN + t];

    const float s = a * (1.0f / HW) * (1.0f / TEMP);
    float ssum = s;
    float lsum = fmaxf(log1pf(-s), -100.0f);

    __shared__ float rs[4], rl[4];
    __shared__ float s0sh;
    #pragma unroll
    for (int off = 32; off; off >>= 1) {
        ssum += __shfl_down(ssum, off);
        lsum += __shfl_down(lsum, off);
    }
    if ((t & 63) == 0) { rs[t >> 6] = ssum; rl[t >> 6] = lsum; }

    if (t < 64) {
        float v = sim0Part[b * 64 + t];
        #pragma unroll
        for (int off = 32; off; off >>= 1) v += __shfl_xor(v, off);
        if (t == 0) s0sh = v * (1.0f / HW);
    }
    __syncthreads();

    if (t == 0) {
        const float S = rs[0] + rs[1] + rs[2] + rs[3];
        const float L = rl[0] + rl[1] + rl[2] + rl[3];
        const float s0 = s0sh;
        const float logp = fmaxf(logf(s0), -100.0f);
        atomicAdd(out + 0, -(logp + L) / ((float)(NEGN + 1) * (float)BB));
        atomicAdd(out + 1, s0 / (float)BB);
        atomicAdd(out + 2, S / (float)NEGN * TEMP / (float)BB);
    }
}

extern "C" void kernel_launch(void* const* d_in, const int* in_sizes, int n_in,
                              void* d_out, int out_size, void* d_ws, size_t ws_size,
                              hipStream_t stream) {
    const float* v1   = (const float*)d_in[0];
    const float* v2   = (const float*)d_in[1];
    const float* img  = (const float*)d_in[2];
    const int*   nidx = (const int*)  d_in[3];

    float*   simPart  = (float*)d_ws;                    // 512*256
    float*   sim0Part = simPart + 512 * NEGN;            // 512
    float*   weight_g = sim0Part + 512;                  // 8192
    float*   z1n_ws   = weight_g + 8192;                 // 8192
    float*   normq_ws = z1n_ws + 8192;                   // 8192
    ushort2* qp       = (ushort2*)(normq_ws + 8192);     // 1,048,576 (4 MB)
    unsigned short* z1t = (unsigned short*)(qp + 1048576); // 512K u16 (1 MB)
    unsigned short* z2t = z1t + 8 * 1024 * 64;             // 512K u16 (1 MB)

    prep<<<1024, 256, 0, stream>>>(v1, v2, img, nidx, qp, weight_g,
                                   z1t, z2t, z1n_ws, normq_ws, sim0Part);
    gemm_mfma<<<512, 256, 0, stream>>>(z1t, z2t, z1n_ws, normq_ws,
                                       qp, weight_g, simPart);
    reduce_out<<<BB, 256, 0, stream>>>(simPart, sim0Part, (float*)d_out);
}